// Round 1
// baseline (5913.371 us; speedup 1.0000x reference)
//
#include <hip/hip_runtime.h>

#define B_    64
#define T_    1024
#define IN_   64
#define H_    512
#define OUT_  64
#define SLOTS 8
#define BH    (64*512)   // elements per h slot
#define NWG   130

typedef _Float16 f16;
typedef _Float16 half8 __attribute__((ext_vector_type(8)));
typedef float    floatx4 __attribute__((ext_vector_type(4)));
typedef unsigned int u32;
typedef unsigned long long u64;

#define MFMA16(a,b,c) __builtin_amdgcn_mfma_f32_16x16x32_f16((a),(b),(c),0,0,0)

// LDS layout (114688 B, 1 WG/CU)
// RED rows padded 16->20 floats: quad stride 80 words == 16 mod 32 -> 2-way (free)
#define XS_OFF   0        // 8KB: L1 x-stage
#define H1S_OFF  8192     // 32KB: recurrent/h1 stage
#define H2S_OFF  40960    // 32KB: h2 stage (L2 pass B)
#define RED_OFF  73728    // 40KB: 4 kq-regions x 2560 floats (4 gates x 32 rows x 20)

__device__ __forceinline__ float sigmoidf_(float x) {
    return 1.0f / (1.0f + __expf(-x));
}
__device__ __forceinline__ float tanhf_(float x) {
    float ax = fabsf(x);
    float e  = __expf(-2.0f * ax);
    float t  = (1.0f - e) / (1.0f + e);
    return x >= 0.0f ? t : -t;
}

// Flags: agent-scope RMW + agent-scope poll (proven R2/R5).
__device__ __forceinline__ void wait_ge(u32* p, u32 v) {
    while (__hip_atomic_load(p, __ATOMIC_RELAXED, __HIP_MEMORY_SCOPE_AGENT) < v)
        __builtin_amdgcn_s_sleep(1);
}
__device__ __forceinline__ void flag_add(u32* p) {
    __hip_atomic_fetch_add(p, 1u, __ATOMIC_RELAXED, __HIP_MEMORY_SCOPE_AGENT);
}
// Data reads: system-scope relaxed load (sc0+sc1, reads IF$ coherence point). Proven R5.
__device__ __forceinline__ u64 aload8(const f16* p) {
    return __hip_atomic_load((const u64*)p, __ATOMIC_RELAXED, __HIP_MEMORY_SCOPE_SYSTEM);
}
// Data publish: RETURNING system-scope exchange; vmcnt retires only after the
// IF$ round-trip, so the pre-flag __syncthreads orders data before flag. Proven R5.
__device__ __forceinline__ void apub8(f16* p, u64 v) {
    u64 old = __hip_atomic_exchange((u64*)p, v, __ATOMIC_RELAXED, __HIP_MEMORY_SCOPE_SYSTEM);
    asm volatile("" : : "v"(old));
}

// ---------------- prep kernels (weights -> fp16 fragment-linear) ----------------
__global__ void pack_w1(const float* __restrict__ Wih, const float* __restrict__ Whh,
                        f16* __restrict__ Wp) {
    int idx = blockIdx.x * 256 + threadIdx.x;
    if (idx >= 4*32*18*512) return;
    int j    = idx & 7;
    int lane = (idx >> 3) & 63;
    int kt   = (idx >> 9) % 18;
    int r    = (idx >> 9) / 18;
    int jt   = r & 31;
    int g    = r >> 5;
    int n = g*512 + jt*16 + (lane & 15);
    int k = kt*32 + (lane >> 4)*8 + j;
    float v = (k < 64) ? Wih[n*64 + k] : Whh[n*512 + (k - 64)];
    Wp[idx] = (f16)v;
}

__global__ void pack_w2(const float* __restrict__ Wih, const float* __restrict__ Whh,
                        f16* __restrict__ Wp) {
    int idx = blockIdx.x * 256 + threadIdx.x;
    if (idx >= 4*32*32*512) return;
    int j    = idx & 7;
    int lane = (idx >> 3) & 63;
    int kt   = (idx >> 9) & 31;
    int r    = idx >> 14;
    int jt   = r & 31;
    int g    = r >> 5;
    int n = g*512 + jt*16 + (lane & 15);
    int k = kt*32 + (lane >> 4)*8 + j;
    float v = (k < 512) ? Wih[n*512 + k] : Whh[n*512 + (k - 512)];
    Wp[idx] = (f16)v;
}

__global__ void pack_wo(const float* __restrict__ Wout, f16* __restrict__ Wp) {
    int idx = blockIdx.x * 256 + threadIdx.x;
    if (idx >= 4*16*512) return;
    int j    = idx & 7;
    int lane = (idx >> 3) & 63;
    int kt   = (idx >> 9) & 15;
    int nt   = idx >> 13;
    int n = nt*16 + (lane & 15);
    int k = kt*32 + (lane >> 4)*8 + j;
    Wp[idx] = (f16)Wout[n*512 + k];
}

__global__ void bias_sum(const float* __restrict__ a1, const float* __restrict__ b1,
                         const float* __restrict__ a2, const float* __restrict__ b2,
                         float* __restrict__ s1, float* __restrict__ s2) {
    int i = blockIdx.x * 256 + threadIdx.x;
    if (i >= 2048) return;
    s1[i] = a1[i] + b1[i];
    s2[i] = a2[i] + b2[i];
}

// ---------------- persistent self-timed kernel ----------------
// WG 0..63:   layer1 (jt = wg&31, bhalf = wg>>5); waves gp=w&1, kq=w>>1 (K-slice)
// WG 64..127: layer2 (v=wg-64: jt=v&31, bhalf=v>>5); same wave split
// WG 128..129: head (bhalf = wg-128)
// h buffers: 8 slots (slot = t&7).
// R6 changes: x register-prefetch (hides x load under publish RT); wait split
// tid0/tid64 (parallel polls); RED row pad 16->20 (kills 4-way bank conflict);
// fused pointwise+publish on tid<128 with c-state in registers (one less
// barrier, no XS h-bounce, no CC LDS).
__global__ __launch_bounds__(512, 1) void lstm_persist(
    const float* __restrict__ x,
    const f16*  __restrict__ W1p,
    const f16*  __restrict__ W2p,
    const f16*  __restrict__ Wop,
    const float* __restrict__ bs1,
    const float* __restrict__ bs2,
    const float* __restrict__ bout,
    f16*  __restrict__ h1buf,   // [8][64][512] fp16
    f16*  __restrict__ h2buf,   // [8][64][512] fp16
    float* __restrict__ y,
    u32*  __restrict__ arr1,    // [2][1024]
    u32*  __restrict__ arr2,    // [2][1024]
    u32*  __restrict__ arrH)    // [2][1024]
{
    __shared__ __align__(16) char smem[114688];
    float* RED = (float*)(smem + RED_OFF);

    const int wg   = blockIdx.x;
    const int tid  = threadIdx.x;
    const int lane = tid & 63;
    const int w    = tid >> 6;
    const int col  = lane & 15;
    const int quad = lane >> 4;

    if (wg < 64) {
        // ================= layer 1 =================
        const int jt = wg & 31, bhalf = wg >> 5;
        const int gp = w & 1, kq = w >> 1;
        half8 wrx[2];
        half8 wrh[2][4];
        if (kq < 2) {
            #pragma unroll
            for (int gi = 0; gi < 2; ++gi)
                wrx[gi] = *(const half8*)(W1p + ((size_t)(((gp*2+gi)*32 + jt)*18 + kq)*64 + lane)*8);
        }
        #pragma unroll
        for (int gi = 0; gi < 2; ++gi)
            #pragma unroll
            for (int k = 0; k < 4; ++k) {
                const int kt = 2 + kq*4 + k;
                wrh[gi][k] = *(const half8*)(W1p + ((size_t)(((gp*2+gi)*32 + jt)*18 + kt)*64 + lane)*8);
            }
        // fused-pointwise thread state (tid<128): 4 gate-cols jt*16+jq*4..+3, row brow
        const int brow = tid >> 2, jq = tid & 3;
        floatx4 bsr4[4];
        if (tid < 128) {
            #pragma unroll
            for (int g = 0; g < 4; ++g)
                bsr4[g] = *(const floatx4*)(bs1 + g*512 + jt*16 + jq*4);
        }
        float cst[4] = {0.f, 0.f, 0.f, 0.f};

        u32* a1 = arr1 + bhalf*1024;
        u32* a2 = arr2 + bhalf*1024;

        // x prefetch: one float4 per thread, one step ahead
        const int lb4 = tid >> 4, kc4 = tid & 15;
        const float* xsrc = x + (size_t)(bhalf*32 + lb4)*T_*(size_t)IN_ + ((kc4 ^ (lb4 & 7)) * 4);
        float4 xpre = *(const float4*)xsrc;   // t=0
        xsrc += IN_;

        for (int t = 0; t < T_; ++t) {
            const int sR = (t + SLOTS - 1) & (SLOTS-1);
            const int sW = t & (SLOTS-1);
            // stash prefetched x_t (registers -> LDS, no global wait)
            *(float4*)(smem + XS_OFF + tid*16) = xpre;
            // parallel polls: tid0 recurrence, tid64 slot backpressure
            if (tid == 0  && t >= 1)     wait_ge(a1 + (t-1), 32u);
            if (tid == 64 && t >= SLOTS) wait_ge(a2 + (t-SLOTS), 32u);
            __syncthreads();
            #pragma unroll
            for (int i = 0; i < 8; ++i) {   // stage h1[t-1]
                const int g2 = i*512 + tid;
                const int lb = g2 >> 7, r = g2 & 127, q = r >> 1, hf = r & 1;
                u64 v = aload8(h1buf + (size_t)sR*BH + (size_t)(bhalf*32 + lb)*H_ + ((q ^ (lb & 7))*8 + hf*4));
                *(u64*)(smem + H1S_OFF + (size_t)(lb*64 + q)*16 + hf*8) = v;
            }
            __syncthreads();
            floatx4 acc[2][2] = {{{0.f,0.f,0.f,0.f},{0.f,0.f,0.f,0.f}},
                                 {{0.f,0.f,0.f,0.f},{0.f,0.f,0.f,0.f}}};
            #pragma unroll
            for (int m = 0; m < 2; ++m) {
                const int lb_a = m*16 + col, sw = lb_a & 7;
                if (kq < 2) {   // x-part: this kq's 32-col tile
                    const int fg = kq*8 + quad*2;
                    float4 u = *(const float4*)(smem + XS_OFF + ((size_t)lb_a*16 + (fg ^ sw))*16);
                    float4 v = *(const float4*)(smem + XS_OFF + ((size_t)lb_a*16 + ((fg+1) ^ sw))*16);
                    half8 a = (half8){(f16)u.x,(f16)u.y,(f16)u.z,(f16)u.w,
                                      (f16)v.x,(f16)v.y,(f16)v.z,(f16)v.w};
                    acc[0][m] = MFMA16(a, wrx[0], acc[0][m]);
                    acc[1][m] = MFMA16(a, wrx[1], acc[1][m]);
                }
                #pragma unroll
                for (int k = 0; k < 4; ++k) {
                    const int kc = kq*16 + k*4 + quad;
                    half8 a = *(const half8*)(smem + H1S_OFF + ((size_t)lb_a*64 + (kc ^ sw))*16);
                    acc[0][m] = MFMA16(a, wrh[0][k], acc[0][m]);
                    acc[1][m] = MFMA16(a, wrh[1][k], acc[1][m]);
                }
            }
            #pragma unroll
            for (int gi = 0; gi < 2; ++gi) {
                const int g = gp*2 + gi;
                #pragma unroll
                for (int m = 0; m < 2; ++m)
                    #pragma unroll
                    for (int r = 0; r < 4; ++r)
                        RED[kq*2560 + g*640 + (m*16 + quad*4 + r)*20 + col] = acc[gi][m][r];
            }
            __syncthreads();
            if (tid < 128) {   // fused kq-sum + pointwise + publish (c in regs)
                floatx4 gt[4];
                #pragma unroll
                for (int g = 0; g < 4; ++g) {
                    floatx4 s = *(const floatx4*)&RED[g*640 + brow*20 + jq*4];
                    #pragma unroll
                    for (int k = 1; k < 4; ++k)
                        s += *(const floatx4*)&RED[k*2560 + g*640 + brow*20 + jq*4];
                    gt[g] = s + bsr4[g];
                }
                union { f16 h4[4]; u64 u; } pk;
                #pragma unroll
                for (int e = 0; e < 4; ++e) {
                    const float i_ = sigmoidf_(gt[0][e]);
                    const float f_ = sigmoidf_(gt[1][e]);
                    const float g_ = tanhf_(gt[2][e]);
                    const float o_ = sigmoidf_(gt[3][e]);
                    const float cn = f_ * cst[e] + i_ * g_;
                    cst[e] = cn;
                    pk.h4[e] = (f16)(o_ * tanhf_(cn));
                }
                apub8(h1buf + (size_t)sW*BH + (size_t)(bhalf*32 + brow)*H_ + jt*16 + jq*4, pk.u);
            }
            // issue next x load: latency hides under the exchange round trip
            if (t + 1 < T_) { xpre = *(const float4*)xsrc; xsrc += IN_; }
            __syncthreads();   // drains exchanges (and xpre) before flag
            if (tid == 0) flag_add(a1 + t);
        }
    } else if (wg < 128) {
        // ================= layer 2 =================
        const int v = wg - 64;
        const int jt = v & 31, bhalf = v >> 5;
        const int gp = w & 1, kq = w >> 1;
        half8 wrA[2][4], wrB[2][4];
        #pragma unroll
        for (int gi = 0; gi < 2; ++gi)
            #pragma unroll
            for (int k = 0; k < 4; ++k) {
                const int ktA = kq*4 + k;        // h1 half (K 0..511)
                const int ktB = 16 + kq*4 + k;   // h2 half (K 512..1023)
                wrA[gi][k] = *(const half8*)(W2p + ((size_t)(((gp*2+gi)*32 + jt)*32 + ktA)*64 + lane)*8);
                wrB[gi][k] = *(const half8*)(W2p + ((size_t)(((gp*2+gi)*32 + jt)*32 + ktB)*64 + lane)*8);
            }
        const int brow = tid >> 2, jq = tid & 3;
        floatx4 bsr4[4];
        if (tid < 128) {
            #pragma unroll
            for (int g = 0; g < 4; ++g)
                bsr4[g] = *(const floatx4*)(bs2 + g*512 + jt*16 + jq*4);
        }
        float cst[4] = {0.f, 0.f, 0.f, 0.f};

        u32* a1 = arr1 + bhalf*1024;
        u32* a2 = arr2 + bhalf*1024;
        u32* aH = arrH + bhalf*1024;

        for (int t2 = 0; t2 < T_; ++t2) {
            const int sH1 = t2 & (SLOTS-1);
            const int sRd = (t2 + SLOTS - 1) & (SLOTS-1);
            const int sW  = t2 & (SLOTS-1);
            // parallel polls: tid0 h1-ready, tid64 head backpressure
            if (tid == 0)                 wait_ge(a1 + t2, 32u);
            if (tid == 64 && t2 >= SLOTS) wait_ge(aH + (t2-SLOTS), 1u);
            __syncthreads();
            #pragma unroll
            for (int i = 0; i < 8; ++i) {   // stage h1[t2]
                const int g2 = i*512 + tid;
                const int lb = g2 >> 7, r = g2 & 127, q = r >> 1, hf = r & 1;
                u64 vv = aload8(h1buf + (size_t)sH1*BH + (size_t)(bhalf*32 + lb)*H_ + ((q ^ (lb & 7))*8 + hf*4));
                *(u64*)(smem + H1S_OFF + (size_t)(lb*64 + q)*16 + hf*8) = vv;
            }
            __syncthreads();
            floatx4 acc[2][2] = {{{0.f,0.f,0.f,0.f},{0.f,0.f,0.f,0.f}},
                                 {{0.f,0.f,0.f,0.f},{0.f,0.f,0.f,0.f}}};
            // ---- pass A (h1 half) — hides the arr2 detect below ----
            #pragma unroll
            for (int m = 0; m < 2; ++m) {
                const int lb_a = m*16 + col, sw = lb_a & 7;
                #pragma unroll
                for (int k = 0; k < 4; ++k) {
                    const int kc = kq*16 + k*4 + quad;
                    half8 a = *(const half8*)(smem + H1S_OFF + ((size_t)lb_a*64 + (kc ^ sw))*16);
                    acc[0][m] = MFMA16(a, wrA[0][k], acc[0][m]);
                    acc[1][m] = MFMA16(a, wrA[1][k], acc[1][m]);
                }
            }
            if (tid == 0 && t2 >= 1) wait_ge(a2 + (t2-1), 32u);    // recurrence
            __syncthreads();
            #pragma unroll
            for (int i = 0; i < 8; ++i) {   // stage h2[t2-1]
                const int g2 = i*512 + tid;
                const int lb = g2 >> 7, r = g2 & 127, q = r >> 1, hf = r & 1;
                u64 vv = aload8(h2buf + (size_t)sRd*BH + (size_t)(bhalf*32 + lb)*H_ + ((q ^ (lb & 7))*8 + hf*4));
                *(u64*)(smem + H2S_OFF + (size_t)(lb*64 + q)*16 + hf*8) = vv;
            }
            __syncthreads();
            // ---- pass B (h2 half) ----
            #pragma unroll
            for (int m = 0; m < 2; ++m) {
                const int lb_a = m*16 + col, sw = lb_a & 7;
                #pragma unroll
                for (int k = 0; k < 4; ++k) {
                    const int kc = kq*16 + k*4 + quad;
                    half8 a = *(const half8*)(smem + H2S_OFF + ((size_t)lb_a*64 + (kc ^ sw))*16);
                    acc[0][m] = MFMA16(a, wrB[0][k], acc[0][m]);
                    acc[1][m] = MFMA16(a, wrB[1][k], acc[1][m]);
                }
            }
            #pragma unroll
            for (int gi = 0; gi < 2; ++gi) {
                const int g = gp*2 + gi;
                #pragma unroll
                for (int m = 0; m < 2; ++m)
                    #pragma unroll
                    for (int r = 0; r < 4; ++r)
                        RED[kq*2560 + g*640 + (m*16 + quad*4 + r)*20 + col] = acc[gi][m][r];
            }
            __syncthreads();
            if (tid < 128) {   // fused kq-sum + pointwise + publish (c in regs)
                floatx4 gt[4];
                #pragma unroll
                for (int g = 0; g < 4; ++g) {
                    floatx4 s = *(const floatx4*)&RED[g*640 + brow*20 + jq*4];
                    #pragma unroll
                    for (int k = 1; k < 4; ++k)
                        s += *(const floatx4*)&RED[k*2560 + g*640 + brow*20 + jq*4];
                    gt[g] = s + bsr4[g];
                }
                union { f16 h4[4]; u64 u; } pk;
                #pragma unroll
                for (int e = 0; e < 4; ++e) {
                    const float i_ = sigmoidf_(gt[0][e]);
                    const float f_ = sigmoidf_(gt[1][e]);
                    const float g_ = tanhf_(gt[2][e]);
                    const float o_ = sigmoidf_(gt[3][e]);
                    const float cn = f_ * cst[e] + i_ * g_;
                    cst[e] = cn;
                    pk.h4[e] = (f16)(o_ * tanhf_(cn));
                }
                apub8(h2buf + (size_t)sW*BH + (size_t)(bhalf*32 + brow)*H_ + jt*16 + jq*4, pk.u);
            }
            __syncthreads();
            if (tid == 0) flag_add(a2 + t2);
        }
    } else {
        // ================= head =================
        const int bhalf = wg - 128;
        const int nt = w & 3, kh = w >> 2;
        half8 wr[8];
        #pragma unroll
        for (int k = 0; k < 8; ++k) {
            const int kt = kh*8 + k;
            wr[k] = *(const half8*)(Wop + ((size_t)(nt*16 + kt)*64 + lane)*8);
        }
        const float boutr = bout[nt*16 + col];
        u32* a2 = arr2 + bhalf*1024;
        u32* aH = arrH + bhalf*1024;
        const int lb0 = col, lb1 = 16 + col;
        const int swz = col & 7;

        for (int t3 = 0; t3 < T_; ++t3) {
            const int sH = t3 & (SLOTS-1);
            if (tid == 0) wait_ge(a2 + t3, 32u);
            __syncthreads();
            #pragma unroll
            for (int i = 0; i < 8; ++i) {   // stage h2[t3]
                const int g2 = i*512 + tid;
                const int lb = g2 >> 7, r = g2 & 127, q = r >> 1, hf = r & 1;
                u64 vv = aload8(h2buf + (size_t)sH*BH + (size_t)(bhalf*32 + lb)*H_ + ((q ^ (lb & 7))*8 + hf*4));
                *(u64*)(smem + H1S_OFF + (size_t)(lb*64 + q)*16 + hf*8) = vv;
            }
            __syncthreads();   // staging drained -> release back-pressure
            if (tid == 0) flag_add(aH + t3);
            floatx4 acc0 = {0.f,0.f,0.f,0.f}, acc1 = {0.f,0.f,0.f,0.f};
            #pragma unroll
            for (int k = 0; k < 8; ++k) {
                const int kc = (kh*8 + k)*4 + quad;
                half8 a0 = *(const half8*)(smem + H1S_OFF + ((size_t)lb0*64 + (kc ^ swz))*16);
                half8 a1v = *(const half8*)(smem + H1S_OFF + ((size_t)lb1*64 + (kc ^ swz))*16);
                acc0 = MFMA16(a0,  wr[k], acc0);
                acc1 = MFMA16(a1v, wr[k], acc1);
            }
            if (kh == 1) {
                #pragma unroll
                for (int r = 0; r < 4; ++r) {
                    RED[(nt*2+0)*320 + (quad*4 + r)*20 + col] = acc0[r];
                    RED[(nt*2+1)*320 + (quad*4 + r)*20 + col] = acc1[r];
                }
            }
            __syncthreads();
            if (kh == 0) {
                #pragma unroll
                for (int r = 0; r < 4; ++r) {
                    const float v0 = acc0[r] + RED[(nt*2+0)*320 + (quad*4 + r)*20 + col] + boutr;
                    const float v1 = acc1[r] + RED[(nt*2+1)*320 + (quad*4 + r)*20 + col] + boutr;
                    const int b0 = bhalf*32 +  0 + quad*4 + r;
                    const int b1 = bhalf*32 + 16 + quad*4 + r;
                    y[((size_t)b0*T_ + t3)*OUT_ + nt*16 + col] = v0;
                    y[((size_t)b1*T_ + t3)*OUT_ + nt*16 + col] = v1;
                }
            }
            __syncthreads();   // RED reuse next step
        }
    }
}

// ---------------- launch ----------------
extern "C" void kernel_launch(void* const* d_in, const int* in_sizes, int n_in,
                              void* d_out, int out_size, void* d_ws, size_t ws_size,
                              hipStream_t stream) {
    const float* x    = (const float*)d_in[0];
    const float* Wih1 = (const float*)d_in[1];
    const float* Whh1 = (const float*)d_in[2];
    const float* bih1 = (const float*)d_in[3];
    const float* bhh1 = (const float*)d_in[4];
    const float* Wih2 = (const float*)d_in[5];
    const float* Whh2 = (const float*)d_in[6];
    const float* bih2 = (const float*)d_in[7];
    const float* bhh2 = (const float*)d_in[8];
    const float* Wout = (const float*)d_in[9];
    const float* bout = (const float*)d_in[10];
    float* y = (float*)d_out;

    char* ws = (char*)d_ws;
    f16*   W1p   = (f16*)(ws + 0);           // 2,359,296 B
    f16*   W2p   = (f16*)(ws + 2359296);     // 4,194,304 B
    f16*   Wop   = (f16*)(ws + 6553600);     //    65,536 B
    float* bs1   = (float*)(ws + 6619136);   //     8,192 B
    float* bs2   = (float*)(ws + 6627328);   //     8,192 B
    f16*   h1buf = (f16*)(ws + 6635520);     // 8 slots = 524,288 B
    f16*   h2buf = (f16*)(ws + 7159808);     // 8 slots = 524,288 B
    u32*   arr1  = (u32*)(ws + 7684096);     //     8,192 B
    u32*   arr2  = (u32*)(ws + 7692288);     //     8,192 B
    u32*   arrH  = (u32*)(ws + 7700480);     //     8,192 B

    // zero h slots (t=-1 state lives in slot 7) + all arrival counters
    hipMemsetAsync(ws + 6635520, 0, 1073152, stream);

    pack_w1<<<4608, 256, 0, stream>>>(Wih1, Whh1, W1p);
    pack_w2<<<8192, 256, 0, stream>>>(Wih2, Whh2, W2p);
    pack_wo<<<128, 256, 0, stream>>>(Wout, Wop);
    bias_sum<<<8, 256, 0, stream>>>(bih1, bhh1, bih2, bhh2, bs1, bs2);

    lstm_persist<<<NWG, 512, 0, stream>>>(x, W1p, W2p, Wop, bs1, bs2, bout,
                                          h1buf, h2buf, y, arr1, arr2, arrH);
}